// Round 13
// baseline (392.275 us; speedup 1.0000x reference)
//
#include <hip/hip_runtime.h>
#include <cstdint>
#include <cstddef>

typedef __attribute__((ext_vector_type(8))) short bf16x8;
typedef __attribute__((ext_vector_type(4))) float f32x4;
typedef __attribute__((ext_vector_type(16))) float f32x16;

static __device__ __forceinline__ unsigned short f2bf(float f) {
    union { float f; unsigned u; } v; v.f = f;
    unsigned r = v.u + 0x7FFFu + ((v.u >> 16) & 1u);
    return (unsigned short)(r >> 16);
}
static __device__ __forceinline__ float bf2f(unsigned short u) {
    union { unsigned u; float f; } v; v.u = ((unsigned)u) << 16; return v.f;
}

// global -> LDS direct copy, 16B per lane. LDS dest is wave-uniform base + lane*16.
static __device__ __forceinline__ void gld_lds16(const void* g, void* l) {
    unsigned loff = (unsigned)(size_t)l;
    loff = (unsigned)__builtin_amdgcn_readfirstlane((int)loff);
    __builtin_amdgcn_global_load_lds(
        (const __attribute__((address_space(1))) unsigned int*)(size_t)g,
        (__attribute__((address_space(3))) unsigned int*)(size_t)loff,
        16, 0, 0);
}

// ---------------- fused fp32 -> bf16 convert (all 5 tensors, one launch) ----------------
__global__ __launch_bounds__(256) void k_cvt5(
    const float* __restrict__ p0, const float* __restrict__ p1,
    const float* __restrict__ p2, const float* __restrict__ p3,
    const float* __restrict__ p4,
    unsigned short* __restrict__ q0, unsigned short* __restrict__ q1,
    unsigned short* __restrict__ q2, unsigned short* __restrict__ q3,
    unsigned short* __restrict__ q4)
{
    const int blk = blockIdx.x;
    const float* in; unsigned short* out; int base;
    if      (blk < 3072)  { in = p0; out = q0; base = blk; }
    else if (blk < 4096)  { in = p1; out = q1; base = blk - 3072; }
    else if (blk < 8192)  { in = p2; out = q2; base = blk - 4096; }
    else if (blk < 12288) { in = p3; out = q3; base = blk - 8192; }
    else                  { in = p4; out = q4; base = blk - 12288; }
    const int i = (base * 256 + threadIdx.x) * 4;
    float4 v = *reinterpret_cast<const float4*>(in + i);
    ushort4 o;
    o.x = f2bf(v.x); o.y = f2bf(v.y); o.z = f2bf(v.z); o.w = f2bf(v.w);
    *reinterpret_cast<ushort4*>(out + i) = o;
}

// ---------------- phase-structured bf16 GEMM: C(MxN) = A(MxK) @ W(NxK)^T ----------------
// MFMA operands SWAPPED (acc holds C^T fragments): per-thread acc[m][n][r] maps to
// row = ...+lr (fixed), col = ...+g*4+r (4 consecutive) -> epilogue packs 4 cols into
// one uint2 store (4x fewer store messages than the C-fragment order).
// KS-way split-K: split sid owns K/KS contiguous k; partial at Cb + sid*M*N (bf16).
template<int BM, int MF, int KS>
__global__ __launch_bounds__(512, 2) void k_gemm8(
    const unsigned short* __restrict__ A, const unsigned short* __restrict__ W,
    float* __restrict__ Cf, unsigned short* __restrict__ Cb,
    const float* __restrict__ bias,
    int M, int N, int K, int scale_cols, float scale, int relu)
{
    __shared__ unsigned short As[2][BM * 64];
    __shared__ unsigned short Bs[2][256 * 64];
    const int tid = threadIdx.x, wid = tid >> 6, lane = tid & 63;
    const int lr = lane & 15, g16 = (lane >> 4) * 16;
    const int wm = wid >> 2, wn = wid & 3;

    const int nbx = N >> 8;
    const int nwg = gridDim.x;
    const int raw = blockIdx.x;
    const int swz = (raw & 7) * (nwg >> 3) + (raw >> 3);
    const int base_grid = nwg / KS;
    const int sid = (KS > 1) ? (swz / base_grid) : 0;
    const int tile = (KS > 1) ? (swz % base_grid) : swz;
    const int bm = (tile / nbx) * BM, bn = (tile % nbx) * 256;
    const int kbeg = sid * (K / KS), kend = kbeg + K / KS;

    const int rin = tid >> 3;
    const int cole = (((tid & 7) * 16) ^ ((rin & 7) << 4)) >> 1;

    auto STAGE = [&](int bb, int kt1) {
        #pragma unroll
        for (int c = 0; c < BM / 64; ++c)
            gld_lds16(A + (size_t)(bm + c * 64 + rin) * K + kt1 + cole,
                      (char*)As[bb] + c * 8192 + wid * 1024);
        #pragma unroll
        for (int c = 0; c < 4; ++c)
            gld_lds16(W + (size_t)(bn + c * 64 + rin) * K + kt1 + cole,
                      (char*)Bs[bb] + c * 8192 + wid * 1024);
    };

    f32x4 acc[MF][4] = {};

    STAGE(0, kbeg);
    STAGE(1, kbeg + 64);      // K/KS >= 128 for all call sites
    int cur = 0;

    for (int kt = kbeg; kt < kend; kt += 64) {
        if (kt + 64 < kend) {
            if constexpr (BM == 256) asm volatile("s_waitcnt vmcnt(8)" ::: "memory");
            else                     asm volatile("s_waitcnt vmcnt(6)" ::: "memory");
        } else {
            asm volatile("s_waitcnt vmcnt(0)" ::: "memory");
        }
        __builtin_amdgcn_s_barrier();

        const char* Ab = (const char*)As[cur];
        const char* Bb = (const char*)Bs[cur];
        bf16x8 bfr[4][2];

        #pragma unroll
        for (int p = 0; p < MF / 2; ++p) {
            bf16x8 af[2][2];
            #pragma unroll
            for (int mi = 0; mi < 2; ++mi)
                #pragma unroll
                for (int kk = 0; kk < 2; ++kk) {
                    const int row = wm * (MF * 16) + (2 * p + mi) * 16 + lr;
                    af[mi][kk] = *reinterpret_cast<const bf16x8*>(
                        Ab + row * 128 + ((kk * 64 + g16) ^ ((row & 7) << 4)));
                }
            if (p == 0) {
                #pragma unroll
                for (int n = 0; n < 4; ++n)
                    #pragma unroll
                    for (int kk = 0; kk < 2; ++kk) {
                        const int row = wn * 64 + n * 16 + lr;
                        bfr[n][kk] = *reinterpret_cast<const bf16x8*>(
                            Bb + row * 128 + ((kk * 64 + g16) ^ ((row & 7) << 4)));
                    }
            }
            __builtin_amdgcn_s_barrier();
            __builtin_amdgcn_s_setprio(1);
            #pragma unroll
            for (int mi = 0; mi < 2; ++mi)
                #pragma unroll
                for (int n = 0; n < 4; ++n)
                    #pragma unroll
                    for (int kk = 0; kk < 2; ++kk)
                        acc[2 * p + mi][n] = __builtin_amdgcn_mfma_f32_16x16x32_bf16(
                            bfr[n][kk], af[mi][kk], acc[2 * p + mi][n], 0, 0, 0);
            __builtin_amdgcn_s_setprio(0);
            __builtin_amdgcn_s_barrier();
        }
        if (kt + 128 < kend) STAGE(cur, kt + 128);
        cur ^= 1;
    }

    // Epilogue: C^T fragment -> row = bm + wm*(MF*16) + m*16 + lr (per-thread fixed per m),
    // cols = bn + wn*64 + n*16 + g*4 + {0..3} consecutive -> one uint2 (or float4) store.
    unsigned short* Cbp = Cb ? Cb + (size_t)sid * M * N : nullptr;
    const int g4 = (lane >> 4) * 4;
    #pragma unroll
    for (int m = 0; m < MF; ++m) {
        const int row = bm + wm * (MF * 16) + m * 16 + lr;
        #pragma unroll
        for (int n = 0; n < 4; ++n) {
            const int col0 = bn + wn * 64 + n * 16 + g4;
            const float sc = (col0 < scale_cols) ? scale : 1.0f;
            float b0 = 0.0f, b1 = 0.0f, b2 = 0.0f, b3 = 0.0f;
            if (bias) {
                float4 bb = *reinterpret_cast<const float4*>(bias + col0);
                b0 = bb.x; b1 = bb.y; b2 = bb.z; b3 = bb.w;
            }
            float v0 = acc[m][n][0] * sc + b0;
            float v1 = acc[m][n][1] * sc + b1;
            float v2 = acc[m][n][2] * sc + b2;
            float v3 = acc[m][n][3] * sc + b3;
            if (relu) {
                v0 = fmaxf(v0, 0.0f); v1 = fmaxf(v1, 0.0f);
                v2 = fmaxf(v2, 0.0f); v3 = fmaxf(v3, 0.0f);
            }
            if (Cbp) {
                unsigned lo, hi;
                asm("v_cvt_pk_bf16_f32 %0, %1, %2" : "=v"(lo) : "v"(v0), "v"(v1));
                asm("v_cvt_pk_bf16_f32 %0, %1, %2" : "=v"(hi) : "v"(v2), "v"(v3));
                uint2 u; u.x = lo; u.y = hi;
                *reinterpret_cast<uint2*>(Cbp + (size_t)row * N + col0) = u;
            } else {
                float4 o; o.x = v0; o.y = v1; o.z = v2; o.w = v3;
                *reinterpret_cast<float4*>(Cf + (size_t)row * N + col0) = o;
            }
        }
    }
}

// ---------------- V pre-transpose (tiled via LDS) ----------------
__global__ __launch_bounds__(256) void k_vtrans(
    const unsigned short* __restrict__ qkv, unsigned short* __restrict__ vt)
{
    __shared__ unsigned short T[64][72];
    const int n = blockIdx.y, b = n >> 4, h = n & 15;
    const int l0 = blockIdx.x * 64;
    const int tid = threadIdx.x;
    {
        const int l = tid >> 2, d = (tid & 3) * 16;
        const unsigned short* p = qkv + (size_t)(l0 + l) * 12288 + b * 3072 + 2048 + h * 64 + d;
        *reinterpret_cast<bf16x8*>(&T[l][d])     = *reinterpret_cast<const bf16x8*>(p);
        *reinterpret_cast<bf16x8*>(&T[l][d + 8]) = *reinterpret_cast<const bf16x8*>(p + 8);
    }
    __syncthreads();
    {
        const int d = tid >> 2, lc = (tid & 3) * 16;
        unsigned short tmp[16];
        #pragma unroll
        for (int j = 0; j < 16; ++j) tmp[j] = T[lc + j][d];
        unsigned short* q = vt + ((size_t)n * 64 + d) * 2048 + l0 + lc;
        *reinterpret_cast<bf16x8*>(q)     = *reinterpret_cast<bf16x8*>(tmp);
        *reinterpret_cast<bf16x8*>(q + 8) = *reinterpret_cast<bf16x8*>(tmp + 8);
    }
}

// ---------------- flash attention: 64 q-rows per wave, shared K/V fragments ----------------
__global__ __launch_bounds__(512) void k_attn(
    const unsigned short* __restrict__ qkv,
    const unsigned short* __restrict__ vt,
    const unsigned char* __restrict__ mask,
    unsigned short* __restrict__ out)
{
    __shared__ unsigned short Ks[2][64 * 64];
    __shared__ unsigned short Vs[2][64 * 64];
    const int tid = threadIdx.x, wid = tid >> 6, lane = tid & 63;
    const int q32 = lane & 31, hi = lane >> 5;
    const int raw = blockIdx.x;                    // 256 blocks
    const int swz = (raw & 7) * 32 + (raw >> 3);   // 8 heads per XCD
    const int n = swz >> 2, qblk = swz & 3;
    const int b = n >> 4, h = n & 15;
    const int qbase = qblk * 512 + wid * 64;       // wave's first q-row (64 rows)
    const size_t SL = 12288;

    bf16x8 qfa[4], qfb[4];
    {
        const unsigned short* qra = qkv + (size_t)(qbase + q32) * SL + (size_t)b * 3072 + h * 64;
        const unsigned short* qrb = qra + 32 * SL;
        #pragma unroll
        for (int t = 0; t < 4; ++t) {
            qfa[t] = *reinterpret_cast<const bf16x8*>(qra + t * 16 + hi * 8);
            qfb[t] = *reinterpret_cast<const bf16x8*>(qrb + t * 16 + hi * 8);
        }
    }

    bool anym;
    {
        const uint4* mp = reinterpret_cast<const uint4*>(mask + b * 2048);
        uint4 m0 = mp[lane * 2], m1 = mp[lane * 2 + 1];
        unsigned mo = m0.x | m0.y | m0.z | m0.w | m1.x | m1.y | m1.z | m1.w;
        anym = __any(mo != 0);
    }

    const int sw = (q32 & 7) << 4;
    int koff[4], voff[2][2];
    #pragma unroll
    for (int t = 0; t < 4; ++t) koff[t] = q32 * 128 + ((t * 32 + hi * 16) ^ sw);
    #pragma unroll
    for (int ks = 0; ks < 2; ++ks)
        #pragma unroll
        for (int hf = 0; hf < 2; ++hf)
            voff[ks][hf] = q32 * 128 + ((ks * 64 + hf * 32 + hi * 16) ^ sw);

    const int soff = wid * 1024 + lane * 16;
    const int srow = soff >> 7;
    const int sbc  = (soff & 127) ^ ((srow & 7) << 4);
    const unsigned short* kgbase = qkv + (size_t)b * 3072 + 1024 + h * 64;
    const unsigned short* vgbase = vt + (size_t)n * 64 * 2048;

    #define STAGE(buf, kt)                                                            \
        do {                                                                          \
            gld_lds16(kgbase + (size_t)((kt) + srow) * SL + (sbc >> 1),               \
                      (char*)Ks[buf] + wid * 1024);                                   \
            gld_lds16(vgbase + (size_t)srow * 2048 + (kt) + (sbc >> 1),               \
                      (char*)Vs[buf] + wid * 1024);                                   \
        } while (0)

    f32x16 o0a = {}, o1a = {}, o2a = {};
    f32x16 o0b = {}, o1b = {}, o2b = {};
    union { unsigned w[4]; bf16x8 v; } onesf;
    onesf.w[0] = 0x3F803F80u; onesf.w[1] = 0x3F803F80u;
    onesf.w[2] = 0x3F803F80u; onesf.w[3] = 0x3F803F80u;

    STAGE(0, 0);
    int cur = 0;

    for (int kt = 0; kt < 2048; kt += 64) {
        __syncthreads();
        if (kt + 64 < 2048) STAGE(cur ^ 1, kt + 64);
        const char* Kb = (const char*)Ks[cur];
        const char* Vb = (const char*)Vs[cur];

        #pragma unroll
        for (int ks = 0; ks < 2; ++ks) {
            bf16x8 kf0 = *reinterpret_cast<const bf16x8*>(Kb + ks * 4096 + koff[0]);
            bf16x8 kf1 = *reinterpret_cast<const bf16x8*>(Kb + ks * 4096 + koff[1]);
            bf16x8 kf2 = *reinterpret_cast<const bf16x8*>(Kb + ks * 4096 + koff[2]);
            bf16x8 kf3 = *reinterpret_cast<const bf16x8*>(Kb + ks * 4096 + koff[3]);
            f32x16 sa = {}, sb = {};
            __builtin_amdgcn_s_setprio(1);
            sa = __builtin_amdgcn_mfma_f32_32x32x16_bf16(kf0, qfa[0], sa, 0, 0, 0);
            sb = __builtin_amdgcn_mfma_f32_32x32x16_bf16(kf0, qfb[0], sb, 0, 0, 0);
            sa = __builtin_amdgcn_mfma_f32_32x32x16_bf16(kf1, qfa[1], sa, 0, 0, 0);
            sb = __builtin_amdgcn_mfma_f32_32x32x16_bf16(kf1, qfb[1], sb, 0, 0, 0);
            sa = __builtin_amdgcn_mfma_f32_32x32x16_bf16(kf2, qfa[2], sa, 0, 0, 0);
            sb = __builtin_amdgcn_mfma_f32_32x32x16_bf16(kf2, qfb[2], sb, 0, 0, 0);
            sa = __builtin_amdgcn_mfma_f32_32x32x16_bf16(kf3, qfa[3], sa, 0, 0, 0);
            sb = __builtin_amdgcn_mfma_f32_32x32x16_bf16(kf3, qfb[3], sb, 0, 0, 0);
            __builtin_amdgcn_s_setprio(0);

            if (anym) {
                #pragma unroll
                for (int r = 0; r < 16; ++r) {
                    const int kl = (r & 3) + 8 * (r >> 2) + 4 * hi;
                    if (mask[b * 2048 + kt + ks * 32 + kl]) { sa[r] = -3e8f; sb[r] = -3e8f; }
                }
            }

            #pragma unroll
            for (int i = 0; i < 16; ++i) sa[i] = __builtin_amdgcn_exp2f(sa[i]);
            #pragma unroll
            for (int i = 0; i < 16; ++i) sb[i] = __builtin_amdgcn_exp2f(sb[i]);

            unsigned pka[8], pkb[8];
            #pragma unroll
            for (int i = 0; i < 8; ++i) {
                asm("v_cvt_pk_bf16_f32 %0, %1, %2" : "=v"(pka[i]) : "v"(sa[2 * i]), "v"(sa[2 * i + 1]));
                asm("v_cvt_pk_bf16_f32 %0, %1, %2" : "=v"(pkb[i]) : "v"(sb[2 * i]), "v"(sb[2 * i + 1]));
            }
            asm("v_permlane32_swap_b32 %0, %1" : "+v"(pka[2]), "+v"(pka[0]));
            asm("v_permlane32_swap_b32 %0, %1" : "+v"(pka[3]), "+v"(pka[1]));
            asm("v_permlane32_swap_b32 %0, %1" : "+v"(pka[6]), "+v"(pka[4]));
            asm("v_permlane32_swap_b32 %0, %1" : "+v"(pka[7]), "+v"(pka[5]));
            asm("v_permlane32_swap_b32 %0, %1" : "+v"(pkb[2]), "+v"(pkb[0]));
            asm("v_permlane32_swap_b32 %0, %1" : "+v"(pkb[3]), "+v"(pkb[1]));
            asm("v_permlane32_swap_b32 %0, %1" : "+v"(pkb[6]), "+v"(pkb[4]));
            asm("v_permlane32_swap_b32 %0, %1" : "+v"(pkb[7]), "+v"(pkb[5]));
            union { unsigned w[4]; bf16x8 v; } pa0, pa1, pb0, pb1;
            pa0.w[0] = pka[0]; pa0.w[1] = pka[1]; pa0.w[2] = pka[2]; pa0.w[3] = pka[3];
            pa1.w[0] = pka[4]; pa1.w[1] = pka[5]; pa1.w[2] = pka[6]; pa1.w[3] = pka[7];
            pb0.w[0] = pkb[0]; pb0.w[1] = pkb[1]; pb0.w[2] = pkb[2]; pb0.w[3] = pkb[3];
            pb1.w[0] = pkb[4]; pb1.w[1] = pkb[5]; pb1.w[2] = pkb[6]; pb1.w[3] = pkb[7];

            const bf16x8 v00 = *reinterpret_cast<const bf16x8*>(Vb + voff[ks][0]);
            const bf16x8 v01 = *reinterpret_cast<const bf16x8*>(Vb + voff[ks][1]);
            const bf16x8 v10 = *reinterpret_cast<const bf16x8*>(Vb + 4096 + voff[ks][0]);
            const bf16x8 v11 = *reinterpret_cast<const bf16x8*>(Vb + 4096 + voff[ks][1]);
            __builtin_amdgcn_s_setprio(1);
            o0a = __builtin_amdgcn_mfma_f32_32x32x16_bf16(v00, pa0.v, o0a, 0, 0, 0);
            o0b = __builtin_amdgcn_mfma_f32_32x32x16_bf16(v00, pb0.v, o0b, 0, 0, 0);
            o0a = __builtin_amdgcn_mfma_f32_32x32x16_bf16(v01, pa1.v, o0a, 0, 0, 0);
            o0b = __builtin_amdgcn_mfma_f32_32x32x16_bf16(v01, pb1.v, o0b, 0, 0, 0);
            o1a = __builtin_amdgcn_mfma_f32_32x32x16_bf16(v10, pa0.v, o1a, 0, 0, 0);
            o1b = __builtin_amdgcn_mfma_f32_32x32x16_bf16(v10, pb0.v, o1b, 0, 0, 0);
            o1a = __builtin_amdgcn_mfma_f32_32x32x16_bf16(v11, pa1.v, o1a, 0, 0, 0);
            o1b = __builtin_amdgcn_mfma_f32_32x32x16_bf16(v11, pb1.v, o1b, 0, 0, 0);
            o2a = __builtin_amdgcn_mfma_f32_32x32x16_bf16(onesf.v, pa0.v, o2a, 0, 0, 0);
            o2b = __builtin_amdgcn_mfma_f32_32x32x16_bf16(onesf.v, pb0.v, o2b, 0, 0, 0);
            o2a = __builtin_amdgcn_mfma_f32_32x32x16_bf16(onesf.v, pa1.v, o2a, 0, 0, 0);
            o2b = __builtin_amdgcn_mfma_f32_32x32x16_bf16(onesf.v, pb1.v, o2b, 0, 0, 0);
            __builtin_amdgcn_s_setprio(0);
        }
        cur ^= 1;
    }
    #undef STAGE

    const float rla = 1.0f / o2a[0];
    const float rlb = 1.0f / o2b[0];
    unsigned short* orowa = out + ((size_t)(qbase + q32) * 4 + b) * 1024 + h * 64;
    unsigned short* orowb = orowa + (size_t)32 * 4096;
    #pragma unroll
    for (int q4 = 0; q4 < 4; ++q4) {
        unsigned w0, w1, w2, w3;
        asm("v_cvt_pk_bf16_f32 %0, %1, %2" : "=v"(w0) : "v"(o0a[q4 * 4 + 0] * rla), "v"(o0a[q4 * 4 + 1] * rla));
        asm("v_cvt_pk_bf16_f32 %0, %1, %2" : "=v"(w1) : "v"(o0a[q4 * 4 + 2] * rla), "v"(o0a[q4 * 4 + 3] * rla));
        asm("v_cvt_pk_bf16_f32 %0, %1, %2" : "=v"(w2) : "v"(o1a[q4 * 4 + 0] * rla), "v"(o1a[q4 * 4 + 1] * rla));
        asm("v_cvt_pk_bf16_f32 %0, %1, %2" : "=v"(w3) : "v"(o1a[q4 * 4 + 2] * rla), "v"(o1a[q4 * 4 + 3] * rla));
        uint2 ua; ua.x = w0; ua.y = w1;
        uint2 ub; ub.x = w2; ub.y = w3;
        *reinterpret_cast<uint2*>(orowa + q4 * 8 + hi * 4)      = ua;
        *reinterpret_cast<uint2*>(orowa + 32 + q4 * 8 + hi * 4) = ub;
        asm("v_cvt_pk_bf16_f32 %0, %1, %2" : "=v"(w0) : "v"(o0b[q4 * 4 + 0] * rlb), "v"(o0b[q4 * 4 + 1] * rlb));
        asm("v_cvt_pk_bf16_f32 %0, %1, %2" : "=v"(w1) : "v"(o0b[q4 * 4 + 2] * rlb), "v"(o0b[q4 * 4 + 3] * rlb));
        asm("v_cvt_pk_bf16_f32 %0, %1, %2" : "=v"(w2) : "v"(o1b[q4 * 4 + 0] * rlb), "v"(o1b[q4 * 4 + 1] * rlb));
        asm("v_cvt_pk_bf16_f32 %0, %1, %2" : "=v"(w3) : "v"(o1b[q4 * 4 + 2] * rlb), "v"(o1b[q4 * 4 + 3] * rlb));
        uint2 uc; uc.x = w0; uc.y = w1;
        uint2 ud; ud.x = w2; ud.y = w3;
        *reinterpret_cast<uint2*>(orowb + q4 * 8 + hi * 4)      = uc;
        *reinterpret_cast<uint2*>(orowb + 32 + q4 * 8 + hi * 4) = ud;
    }
}

// ---------------- residual add + LayerNorm: bf16 x + bf16 y -> bf16 or fp32 ----------------
template<int OUTF>
__global__ __launch_bounds__(256) void k_add_ln(
    const unsigned short* __restrict__ x, const unsigned short* __restrict__ y,
    const float* __restrict__ gamma, const float* __restrict__ beta,
    float* __restrict__ outf, unsigned short* __restrict__ outb)
{
    const int row = blockIdx.x * 4 + (threadIdx.x >> 6);
    const int lane = threadIdx.x & 63;
    const size_t base = (size_t)row * 1024;
    float v[16];
    float s = 0.0f, ss = 0.0f;
    #pragma unroll
    for (int i = 0; i < 4; ++i) {
        const int c = lane * 4 + i * 256;
        ushort4 a = *reinterpret_cast<const ushort4*>(x + base + c);
        ushort4 d = *reinterpret_cast<const ushort4*>(y + base + c);
        v[i * 4 + 0] = bf2f(a.x) + bf2f(d.x); v[i * 4 + 1] = bf2f(a.y) + bf2f(d.y);
        v[i * 4 + 2] = bf2f(a.z) + bf2f(d.z); v[i * 4 + 3] = bf2f(a.w) + bf2f(d.w);
        #pragma unroll
        for (int j = 0; j < 4; ++j) { s += v[i * 4 + j]; ss += v[i * 4 + j] * v[i * 4 + j]; }
    }
    #pragma unroll
    for (int o = 1; o < 64; o <<= 1) { s += __shfl_xor(s, o); ss += __shfl_xor(ss, o); }
    const float mu = s * (1.0f / 1024.0f);
    const float var = ss * (1.0f / 1024.0f) - mu * mu;
    const float rstd = rsqrtf(var + 1e-5f);
    #pragma unroll
    for (int i = 0; i < 4; ++i) {
        const int c = lane * 4 + i * 256;
        float4 gq = *reinterpret_cast<const float4*>(gamma + c);
        float4 bq = *reinterpret_cast<const float4*>(beta + c);
        float o0 = (v[i * 4 + 0] - mu) * rstd * gq.x + bq.x;
        float o1 = (v[i * 4 + 1] - mu) * rstd * gq.y + bq.y;
        float o2 = (v[i * 4 + 2] - mu) * rstd * gq.z + bq.z;
        float o3 = (v[i * 4 + 3] - mu) * rstd * gq.w + bq.w;
        if (OUTF) {
            float4 o; o.x = o0; o.y = o1; o.z = o2; o.w = o3;
            *reinterpret_cast<float4*>(outf + base + c) = o;
        } else {
            ushort4 ob;
            ob.x = f2bf(o0); ob.y = f2bf(o1); ob.z = f2bf(o2); ob.w = f2bf(o3);
            *reinterpret_cast<ushort4*>(outb + base + c) = ob;
        }
    }
}

// ---------------- residual + 2 partials + bias, then LayerNorm (fp32 out) ----------------
__global__ __launch_bounds__(256) void k_add_ln3(
    const unsigned short* __restrict__ x,
    const unsigned short* __restrict__ y0, const unsigned short* __restrict__ y1,
    const float* __restrict__ bias,
    const float* __restrict__ gamma, const float* __restrict__ beta,
    float* __restrict__ outf)
{
    const int row = blockIdx.x * 4 + (threadIdx.x >> 6);
    const int lane = threadIdx.x & 63;
    const size_t base = (size_t)row * 1024;
    float v[16];
    float s = 0.0f, ss = 0.0f;
    #pragma unroll
    for (int i = 0; i < 4; ++i) {
        const int c = lane * 4 + i * 256;
        ushort4 a  = *reinterpret_cast<const ushort4*>(x + base + c);
        ushort4 d0 = *reinterpret_cast<const ushort4*>(y0 + base + c);
        ushort4 d1 = *reinterpret_cast<const ushort4*>(y1 + base + c);
        float4 bb  = *reinterpret_cast<const float4*>(bias + c);
        v[i * 4 + 0] = bf2f(a.x) + bf2f(d0.x) + bf2f(d1.x) + bb.x;
        v[i * 4 + 1] = bf2f(a.y) + bf2f(d0.y) + bf2f(d1.y) + bb.y;
        v[i * 4 + 2] = bf2f(a.z) + bf2f(d0.z) + bf2f(d1.z) + bb.z;
        v[i * 4 + 3] = bf2f(a.w) + bf2f(d0.w) + bf2f(d1.w) + bb.w;
        #pragma unroll
        for (int j = 0; j < 4; ++j) { s += v[i * 4 + j]; ss += v[i * 4 + j] * v[i * 4 + j]; }
    }
    #pragma unroll
    for (int o = 1; o < 64; o <<= 1) { s += __shfl_xor(s, o); ss += __shfl_xor(ss, o); }
    const float mu = s * (1.0f / 1024.0f);
    const float var = ss * (1.0f / 1024.0f) - mu * mu;
    const float rstd = rsqrtf(var + 1e-5f);
    #pragma unroll
    for (int i = 0; i < 4; ++i) {
        const int c = lane * 4 + i * 256;
        float4 gq = *reinterpret_cast<const float4*>(gamma + c);
        float4 bq = *reinterpret_cast<const float4*>(beta + c);
        float4 o;
        o.x = (v[i * 4 + 0] - mu) * rstd * gq.x + bq.x;
        o.y = (v[i * 4 + 1] - mu) * rstd * gq.y + bq.y;
        o.z = (v[i * 4 + 2] - mu) * rstd * gq.z + bq.z;
        o.w = (v[i * 4 + 3] - mu) * rstd * gq.w + bq.w;
        *reinterpret_cast<float4*>(outf + base + c) = o;
    }
}

extern "C" void kernel_launch(void* const* d_in, const int* in_sizes, int n_in,
                              void* d_out, int out_size, void* d_ws, size_t ws_size,
                              hipStream_t stream) {
    const float* src  = (const float*)d_in[0];
    const unsigned char* mask = (const unsigned char*)d_in[1];
    const float* w_qkv = (const float*)d_in[2];
    const float* fc_w = (const float*)d_in[3];
    const float* fc_b = (const float*)d_in[4];
    const float* w1   = (const float*)d_in[5];
    const float* b1   = (const float*)d_in[6];
    const float* w2   = (const float*)d_in[7];
    const float* b2   = (const float*)d_in[8];
    const float* g1   = (const float*)d_in[9];
    const float* be1  = (const float*)d_in[10];
    const float* g2   = (const float*)d_in[11];
    const float* be2  = (const float*)d_in[12];
    float* out = (float*)d_out;

    char* ws = (char*)d_ws;
    size_t o = 0;
    auto take = [&](size_t nbytes) { size_t p = o; o += (nbytes + 255) & ~(size_t)255; return p; };
    unsigned short* wqkv_b = (unsigned short*)(ws + take((size_t)3072 * 1024 * 2));
    unsigned short* fcw_b  = (unsigned short*)(ws + take((size_t)1024 * 1024 * 2));
    unsigned short* w1_b   = (unsigned short*)(ws + take((size_t)4096 * 1024 * 2));
    unsigned short* w2_b   = (unsigned short*)(ws + take((size_t)1024 * 4096 * 2));
    unsigned short* src_b  = (unsigned short*)(ws + take((size_t)8192 * 1024 * 2));
    unsigned short* qkv_b  = (unsigned short*)(ws + take((size_t)8192 * 3072 * 2));
    unsigned short* attn_b = (unsigned short*)(ws + take((size_t)8192 * 1024 * 2));
    unsigned short* h_b    = (unsigned short*)(ws + take((size_t)8192 * 4096 * 2));
    // proj bf16 out + FFN2 split-K partials live in the 48MB qkv region (dead after attn)
    unsigned short* proj_b = qkv_b;
    unsigned short* part_b = qkv_b;      // [2][8192*1024] for FFN2 partials
    unsigned short* x1_b   = src_b;      // LN1 rewrites src_b in place
    unsigned short* vt_b   = h_b;

    // 1) fp32 -> bf16 converts (single launch)
    k_cvt5<<<dim3(20480), 256, 0, stream>>>(w_qkv, fc_w, w1, w2, src,
                                            wqkv_b, fcw_b, w1_b, w2_b, src_b);

    // 2) QKV GEMM, BM=128 (grid 768); Q columns pre-scaled by LOG2E/8
    k_gemm8<128, 4, 1><<<dim3((8192 / 128) * (3072 / 256)), 512, 0, stream>>>(
        src_b, wqkv_b, nullptr, qkv_b, nullptr, 8192, 3072, 1024, 1024, 0.18033688011112042f, 0);

    // 2b) V pre-transpose
    k_vtrans<<<dim3(32, 64), 256, 0, stream>>>(qkv_b, vt_b);

    // 3) flash attention (8-wave blocks, 512 q-rows each, 64 q/wave)
    k_attn<<<dim3(256), 512, 0, stream>>>(qkv_b, vt_b, mask, attn_b);

    // 4) output projection (+fc_b), direct BM=128/MF=4, bf16 out
    k_gemm8<128, 4, 1><<<dim3((8192 / 128) * (1024 / 256)), 512, 0, stream>>>(
        attn_b, fcw_b, nullptr, proj_b, fc_b, 8192, 1024, 1024, 0, 1.0f, 0);

    // 5) residual + LN1 -> x1 (bf16, in-place over src_b)
    k_add_ln<0><<<dim3(8192 / 4), 256, 0, stream>>>(src_b, proj_b, g1, be1, nullptr, x1_b);

    // 6) FFN1: relu(x1 @ w1^T + b1), bf16 out
    k_gemm8<256, 8, 1><<<dim3((8192 / 256) * (4096 / 256)), 512, 0, stream>>>(
        x1_b, w1_b, nullptr, h_b, b1, 8192, 4096, 1024, 0, 1.0f, 1);

    // 7) FFN2: split-K=2 (K=2048/part), bf16 partials (b2 folded into LN2)
    k_gemm8<256, 8, 2><<<dim3((8192 / 256) * (1024 / 256) * 2), 512, 0, stream>>>(
        h_b, w2_b, nullptr, part_b, nullptr, 8192, 1024, 4096, 0, 1.0f, 0);

    // 8) x1 + partials + b2, LN2 -> d_out (fp32)
    k_add_ln3<<<dim3(8192 / 4), 256, 0, stream>>>(
        x1_b, part_b, part_b + (size_t)8192 * 1024, b2, g2, be2, out);
}

// Round 15
// 389.780 us; speedup vs baseline: 1.0064x; 1.0064x over previous
//
#include <hip/hip_runtime.h>
#include <cstdint>
#include <cstddef>

typedef __attribute__((ext_vector_type(8))) short bf16x8;
typedef __attribute__((ext_vector_type(4))) float f32x4;
typedef __attribute__((ext_vector_type(16))) float f32x16;

static __device__ __forceinline__ unsigned short f2bf(float f) {
    union { float f; unsigned u; } v; v.f = f;
    unsigned r = v.u + 0x7FFFu + ((v.u >> 16) & 1u);
    return (unsigned short)(r >> 16);
}
static __device__ __forceinline__ float bf2f(unsigned short u) {
    union { unsigned u; float f; } v; v.u = ((unsigned)u) << 16; return v.f;
}

// global -> LDS direct copy, 16B per lane. LDS dest is wave-uniform base + lane*16.
static __device__ __forceinline__ void gld_lds16(const void* g, void* l) {
    unsigned loff = (unsigned)(size_t)l;
    loff = (unsigned)__builtin_amdgcn_readfirstlane((int)loff);
    __builtin_amdgcn_global_load_lds(
        (const __attribute__((address_space(1))) unsigned int*)(size_t)g,
        (__attribute__((address_space(3))) unsigned int*)(size_t)loff,
        16, 0, 0);
}

// ---------------- fused fp32 -> bf16 convert (all 5 tensors, one launch) ----------------
__global__ __launch_bounds__(256) void k_cvt5(
    const float* __restrict__ p0, const float* __restrict__ p1,
    const float* __restrict__ p2, const float* __restrict__ p3,
    const float* __restrict__ p4,
    unsigned short* __restrict__ q0, unsigned short* __restrict__ q1,
    unsigned short* __restrict__ q2, unsigned short* __restrict__ q3,
    unsigned short* __restrict__ q4)
{
    const int blk = blockIdx.x;
    const float* in; unsigned short* out; int base;
    if      (blk < 3072)  { in = p0; out = q0; base = blk; }
    else if (blk < 4096)  { in = p1; out = q1; base = blk - 3072; }
    else if (blk < 8192)  { in = p2; out = q2; base = blk - 4096; }
    else if (blk < 12288) { in = p3; out = q3; base = blk - 8192; }
    else                  { in = p4; out = q4; base = blk - 12288; }
    const int i = (base * 256 + threadIdx.x) * 4;
    float4 v = *reinterpret_cast<const float4*>(in + i);
    ushort4 o;
    o.x = f2bf(v.x); o.y = f2bf(v.y); o.z = f2bf(v.z); o.w = f2bf(v.w);
    *reinterpret_cast<ushort4*>(out + i) = o;
}

// ---------------- phase-structured bf16 GEMM: C(MxN) = A(MxK) @ W(NxK)^T ----------------
// Swapped operands (acc = C^T frags -> vectorized epilogue). Staging for tile t+2 is
// spread across tile t's phases, but ONLY into LDS regions whose last reader phase has
// already closed (barrier argument): B chunks from phase 1; A chunks 0/2 from phase 2
// (their readers finish in phase 1); A chunks 1/3 only after the tile's final barrier.
// KS-way split-K: partial at Cb + sid*M*N (bf16).
template<int BM, int MF, int KS>
__global__ __launch_bounds__(512, 2) void k_gemm8(
    const unsigned short* __restrict__ A, const unsigned short* __restrict__ W,
    float* __restrict__ Cf, unsigned short* __restrict__ Cb,
    const float* __restrict__ bias,
    int M, int N, int K, int scale_cols, float scale, int relu)
{
    __shared__ unsigned short As[2][BM * 64];
    __shared__ unsigned short Bs[2][256 * 64];
    const int tid = threadIdx.x, wid = tid >> 6, lane = tid & 63;
    const int lr = lane & 15, g16 = (lane >> 4) * 16;
    const int wm = wid >> 2, wn = wid & 3;

    const int nbx = N >> 8;
    const int nwg = gridDim.x;
    const int raw = blockIdx.x;
    const int swz = (raw & 7) * (nwg >> 3) + (raw >> 3);
    const int base_grid = nwg / KS;
    const int sid = (KS > 1) ? (swz / base_grid) : 0;
    const int tile = (KS > 1) ? (swz % base_grid) : swz;
    const int bm = (tile / nbx) * BM, bn = (tile % nbx) * 256;
    const int kbeg = sid * (K / KS), kend = kbeg + K / KS;

    const int rin = tid >> 3;
    const int cole = (((tid & 7) * 16) ^ ((rin & 7) << 4)) >> 1;

    auto STAGE_A = [&](int bb, int kt1, int c) {
        gld_lds16(A + (size_t)(bm + c * 64 + rin) * K + kt1 + cole,
                  (char*)As[bb] + c * 8192 + wid * 1024);
    };
    auto STAGE_B = [&](int bb, int kt1, int c) {
        gld_lds16(W + (size_t)(bn + c * 64 + rin) * K + kt1 + cole,
                  (char*)Bs[bb] + c * 8192 + wid * 1024);
    };
    auto STAGE_ALL = [&](int bb, int kt1) {
        #pragma unroll
        for (int c = 0; c < BM / 64; ++c) STAGE_A(bb, kt1, c);
        #pragma unroll
        for (int c = 0; c < 4; ++c) STAGE_B(bb, kt1, c);
    };

    f32x4 acc[MF][4] = {};

    STAGE_ALL(0, kbeg);
    STAGE_ALL(1, kbeg + 64);      // K/KS >= 128 for all call sites
    int cur = 0;

    for (int kt = kbeg; kt < kend; kt += 64) {
        if (kt + 64 < kend) {
            if constexpr (BM == 256) asm volatile("s_waitcnt vmcnt(8)" ::: "memory");
            else                     asm volatile("s_waitcnt vmcnt(6)" ::: "memory");
        } else {
            asm volatile("s_waitcnt vmcnt(0)" ::: "memory");
        }
        __builtin_amdgcn_s_barrier();

        const char* Ab = (const char*)As[cur];
        const char* Bb = (const char*)Bs[cur];
        const bool stg = (kt + 128 < kend);
        const int nkt = kt + 128;
        bf16x8 bfr[4][2];

        #pragma unroll
        for (int p = 0; p < MF / 2; ++p) {
            bf16x8 af[2][2];
            #pragma unroll
            for (int mi = 0; mi < 2; ++mi)
                #pragma unroll
                for (int kk = 0; kk < 2; ++kk) {
                    const int row = wm * (MF * 16) + (2 * p + mi) * 16 + lr;
                    af[mi][kk] = *reinterpret_cast<const bf16x8*>(
                        Ab + row * 128 + ((kk * 64 + g16) ^ ((row & 7) << 4)));
                }
            if (p == 0) {
                #pragma unroll
                for (int n = 0; n < 4; ++n)
                    #pragma unroll
                    for (int kk = 0; kk < 2; ++kk) {
                        const int row = wn * 64 + n * 16 + lr;
                        bfr[n][kk] = *reinterpret_cast<const bf16x8*>(
                            Bb + row * 128 + ((kk * 64 + g16) ^ ((row & 7) << 4)));
                    }
            }
            // spread next-next-tile staging into regions whose readers have finished:
            // B chunks (read only in phase 0) -> from phase 1.
            // A chunks 0,2 (read in phases 0-1) -> from phase 2. A chunks 1,3 -> tile end.
            if (stg) {
                if constexpr (MF == 8) {
                    if (p == 1) { STAGE_B(cur, nkt, 0); STAGE_B(cur, nkt, 1); }
                    if (p == 2) { STAGE_B(cur, nkt, 2); STAGE_B(cur, nkt, 3); STAGE_A(cur, nkt, 0); }
                    if (p == 3) { STAGE_A(cur, nkt, 2); }
                } else {
                    if (p == 1) { STAGE_B(cur, nkt, 0); STAGE_B(cur, nkt, 1);
                                  STAGE_B(cur, nkt, 2); STAGE_B(cur, nkt, 3); }
                }
            }
            __builtin_amdgcn_s_barrier();
            __builtin_amdgcn_s_setprio(1);
            #pragma unroll
            for (int mi = 0; mi < 2; ++mi)
                #pragma unroll
                for (int n = 0; n < 4; ++n)
                    #pragma unroll
                    for (int kk = 0; kk < 2; ++kk)
                        acc[2 * p + mi][n] = __builtin_amdgcn_mfma_f32_16x16x32_bf16(
                            bfr[n][kk], af[mi][kk], acc[2 * p + mi][n], 0, 0, 0);
            __builtin_amdgcn_s_setprio(0);
            __builtin_amdgcn_s_barrier();
        }
        // remaining A chunks: readers span the tile's last phases -> stage after final barrier
        if (stg) {
            if constexpr (MF == 8) { STAGE_A(cur, nkt, 1); STAGE_A(cur, nkt, 3); }
            else                   { STAGE_A(cur, nkt, 0); STAGE_A(cur, nkt, 1); }
        }
        cur ^= 1;
    }

    // Epilogue: C^T fragment -> row fixed per m, 4 consecutive cols -> one uint2/float4.
    unsigned short* Cbp = Cb ? Cb + (size_t)sid * M * N : nullptr;
    const int g4 = (lane >> 4) * 4;
    #pragma unroll
    for (int m = 0; m < MF; ++m) {
        const int row = bm + wm * (MF * 16) + m * 16 + lr;
        #pragma unroll
        for (int n = 0; n < 4; ++n) {
            const int col0 = bn + wn * 64 + n * 16 + g4;
            const float sc = (col0 < scale_cols) ? scale : 1.0f;
            float b0 = 0.0f, b1 = 0.0f, b2 = 0.0f, b3 = 0.0f;
            if (bias) {
                float4 bb = *reinterpret_cast<const float4*>(bias + col0);
                b0 = bb.x; b1 = bb.y; b2 = bb.z; b3 = bb.w;
            }
            float v0 = acc[m][n][0] * sc + b0;
            float v1 = acc[m][n][1] * sc + b1;
            float v2 = acc[m][n][2] * sc + b2;
            float v3 = acc[m][n][3] * sc + b3;
            if (relu) {
                v0 = fmaxf(v0, 0.0f); v1 = fmaxf(v1, 0.0f);
                v2 = fmaxf(v2, 0.0f); v3 = fmaxf(v3, 0.0f);
            }
            if (Cbp) {
                unsigned lo, hi;
                asm("v_cvt_pk_bf16_f32 %0, %1, %2" : "=v"(lo) : "v"(v0), "v"(v1));
                asm("v_cvt_pk_bf16_f32 %0, %1, %2" : "=v"(hi) : "v"(v2), "v"(v3));
                uint2 u; u.x = lo; u.y = hi;
                *reinterpret_cast<uint2*>(Cbp + (size_t)row * N + col0) = u;
            } else {
                float4 o; o.x = v0; o.y = v1; o.z = v2; o.w = v3;
                *reinterpret_cast<float4*>(Cf + (size_t)row * N + col0) = o;
            }
        }
    }
}

// ---------------- V pre-transpose (tiled via LDS) ----------------
__global__ __launch_bounds__(256) void k_vtrans(
    const unsigned short* __restrict__ qkv, unsigned short* __restrict__ vt)
{
    __shared__ unsigned short T[64][72];
    const int n = blockIdx.y, b = n >> 4, h = n & 15;
    const int l0 = blockIdx.x * 64;
    const int tid = threadIdx.x;
    {
        const int l = tid >> 2, d = (tid & 3) * 16;
        const unsigned short* p = qkv + (size_t)(l0 + l) * 12288 + b * 3072 + 2048 + h * 64 + d;
        *reinterpret_cast<bf16x8*>(&T[l][d])     = *reinterpret_cast<const bf16x8*>(p);
        *reinterpret_cast<bf16x8*>(&T[l][d + 8]) = *reinterpret_cast<const bf16x8*>(p + 8);
    }
    __syncthreads();
    {
        const int d = tid >> 2, lc = (tid & 3) * 16;
        unsigned short tmp[16];
        #pragma unroll
        for (int j = 0; j < 16; ++j) tmp[j] = T[lc + j][d];
        unsigned short* q = vt + ((size_t)n * 64 + d) * 2048 + l0 + lc;
        *reinterpret_cast<bf16x8*>(q)     = *reinterpret_cast<bf16x8*>(tmp);
        *reinterpret_cast<bf16x8*>(q + 8) = *reinterpret_cast<bf16x8*>(tmp + 8);
    }
}

// ---------------- flash attention: 64 q-rows per wave, shared K/V fragments ----------------
__global__ __launch_bounds__(512) void k_attn(
    const unsigned short* __restrict__ qkv,
    const unsigned short* __restrict__ vt,
    const unsigned char* __restrict__ mask,
    unsigned short* __restrict__ out)
{
    __shared__ unsigned short Ks[2][64 * 64];
    __shared__ unsigned short Vs[2][64 * 64];
    const int tid = threadIdx.x, wid = tid >> 6, lane = tid & 63;
    const int q32 = lane & 31, hi = lane >> 5;
    const int raw = blockIdx.x;                    // 256 blocks
    const int swz = (raw & 7) * 32 + (raw >> 3);   // 8 heads per XCD
    const int n = swz >> 2, qblk = swz & 3;
    const int b = n >> 4, h = n & 15;
    const int qbase = qblk * 512 + wid * 64;       // wave's first q-row (64 rows)
    const size_t SL = 12288;

    bf16x8 qfa[4], qfb[4];
    {
        const unsigned short* qra = qkv + (size_t)(qbase + q32) * SL + (size_t)b * 3072 + h * 64;
        const unsigned short* qrb = qra + 32 * SL;
        #pragma unroll
        for (int t = 0; t < 4; ++t) {
            qfa[t] = *reinterpret_cast<const bf16x8*>(qra + t * 16 + hi * 8);
            qfb[t] = *reinterpret_cast<const bf16x8*>(qrb + t * 16 + hi * 8);
        }
    }

    bool anym;
    {
        const uint4* mp = reinterpret_cast<const uint4*>(mask + b * 2048);
        uint4 m0 = mp[lane * 2], m1 = mp[lane * 2 + 1];
        unsigned mo = m0.x | m0.y | m0.z | m0.w | m1.x | m1.y | m1.z | m1.w;
        anym = __any(mo != 0);
    }

    const int sw = (q32 & 7) << 4;
    int koff[4], voff[2][2];
    #pragma unroll
    for (int t = 0; t < 4; ++t) koff[t] = q32 * 128 + ((t * 32 + hi * 16) ^ sw);
    #pragma unroll
    for (int ks = 0; ks < 2; ++ks)
        #pragma unroll
        for (int hf = 0; hf < 2; ++hf)
            voff[ks][hf] = q32 * 128 + ((ks * 64 + hf * 32 + hi * 16) ^ sw);

    const int soff = wid * 1024 + lane * 16;
    const int srow = soff >> 7;
    const int sbc  = (soff & 127) ^ ((srow & 7) << 4);
    const unsigned short* kgbase = qkv + (size_t)b * 3072 + 1024 + h * 64;
    const unsigned short* vgbase = vt + (size_t)n * 64 * 2048;

    #define STAGE(buf, kt)                                                            \
        do {                                                                          \
            gld_lds16(kgbase + (size_t)((kt) + srow) * SL + (sbc >> 1),               \
                      (char*)Ks[buf] + wid * 1024);                                   \
            gld_lds16(vgbase + (size_t)srow * 2048 + (kt) + (sbc >> 1),               \
                      (char*)Vs[buf] + wid * 1024);                                   \
        } while (0)

    f32x16 o0a = {}, o1a = {}, o2a = {};
    f32x16 o0b = {}, o1b = {}, o2b = {};
    union { unsigned w[4]; bf16x8 v; } onesf;
    onesf.w[0] = 0x3F803F80u; onesf.w[1] = 0x3F803F80u;
    onesf.w[2] = 0x3F803F80u; onesf.w[3] = 0x3F803F80u;

    STAGE(0, 0);
    int cur = 0;

    for (int kt = 0; kt < 2048; kt += 64) {
        __syncthreads();
        if (kt + 64 < 2048) STAGE(cur ^ 1, kt + 64);
        const char* Kb = (const char*)Ks[cur];
        const char* Vb = (const char*)Vs[cur];

        #pragma unroll
        for (int ks = 0; ks < 2; ++ks) {
            bf16x8 kf0 = *reinterpret_cast<const bf16x8*>(Kb + ks * 4096 + koff[0]);
            bf16x8 kf1 = *reinterpret_cast<const bf16x8*>(Kb + ks * 4096 + koff[1]);
            bf16x8 kf2 = *reinterpret_cast<const bf16x8*>(Kb + ks * 4096 + koff[2]);
            bf16x8 kf3 = *reinterpret_cast<const bf16x8*>(Kb + ks * 4096 + koff[3]);
            f32x16 sa = {}, sb = {};
            __builtin_amdgcn_s_setprio(1);
            sa = __builtin_amdgcn_mfma_f32_32x32x16_bf16(kf0, qfa[0], sa, 0, 0, 0);
            sb = __builtin_amdgcn_mfma_f32_32x32x16_bf16(kf0, qfb[0], sb, 0, 0, 0);
            sa = __builtin_amdgcn_mfma_f32_32x32x16_bf16(kf1, qfa[1], sa, 0, 0, 0);
            sb = __builtin_amdgcn_mfma_f32_32x32x16_bf16(kf1, qfb[1], sb, 0, 0, 0);
            sa = __builtin_amdgcn_mfma_f32_32x32x16_bf16(kf2, qfa[2], sa, 0, 0, 0);
            sb = __builtin_amdgcn_mfma_f32_32x32x16_bf16(kf2, qfb[2], sb, 0, 0, 0);
            sa = __builtin_amdgcn_mfma_f32_32x32x16_bf16(kf3, qfa[3], sa, 0, 0, 0);
            sb = __builtin_amdgcn_mfma_f32_32x32x16_bf16(kf3, qfb[3], sb, 0, 0, 0);
            __builtin_amdgcn_s_setprio(0);

            if (anym) {
                #pragma unroll
                for (int r = 0; r < 16; ++r) {
                    const int kl = (r & 3) + 8 * (r >> 2) + 4 * hi;
                    if (mask[b * 2048 + kt + ks * 32 + kl]) { sa[r] = -3e8f; sb[r] = -3e8f; }
                }
            }

            #pragma unroll
            for (int i = 0; i < 16; ++i) sa[i] = __builtin_amdgcn_exp2f(sa[i]);
            #pragma unroll
            for (int i = 0; i < 16; ++i) sb[i] = __builtin_amdgcn_exp2f(sb[i]);

            unsigned pka[8], pkb[8];
            #pragma unroll
            for (int i = 0; i < 8; ++i) {
                asm("v_cvt_pk_bf16_f32 %0, %1, %2" : "=v"(pka[i]) : "v"(sa[2 * i]), "v"(sa[2 * i + 1]));
                asm("v_cvt_pk_bf16_f32 %0, %1, %2" : "=v"(pkb[i]) : "v"(sb[2 * i]), "v"(sb[2 * i + 1]));
            }
            asm("v_permlane32_swap_b32 %0, %1" : "+v"(pka[2]), "+v"(pka[0]));
            asm("v_permlane32_swap_b32 %0, %1" : "+v"(pka[3]), "+v"(pka[1]));
            asm("v_permlane32_swap_b32 %0, %1" : "+v"(pka[6]), "+v"(pka[4]));
            asm("v_permlane32_swap_b32 %0, %1" : "+v"(pka[7]), "+v"(pka[5]));
            asm("v_permlane32_swap_b32 %0, %1" : "+v"(pkb[2]), "+v"(pkb[0]));
            asm("v_permlane32_swap_b32 %0, %1" : "+v"(pkb[3]), "+v"(pkb[1]));
            asm("v_permlane32_swap_b32 %0, %1" : "+v"(pkb[6]), "+v"(pkb[4]));
            asm("v_permlane32_swap_b32 %0, %1" : "+v"(pkb[7]), "+v"(pkb[5]));
            union { unsigned w[4]; bf16x8 v; } pa0, pa1, pb0, pb1;
            pa0.w[0] = pka[0]; pa0.w[1] = pka[1]; pa0.w[2] = pka[2]; pa0.w[3] = pka[3];
            pa1.w[0] = pka[4]; pa1.w[1] = pka[5]; pa1.w[2] = pka[6]; pa1.w[3] = pka[7];
            pb0.w[0] = pkb[0]; pb0.w[1] = pkb[1]; pb0.w[2] = pkb[2]; pb0.w[3] = pkb[3];
            pb1.w[0] = pkb[4]; pb1.w[1] = pkb[5]; pb1.w[2] = pkb[6]; pb1.w[3] = pkb[7];

            const bf16x8 v00 = *reinterpret_cast<const bf16x8*>(Vb + voff[ks][0]);
            const bf16x8 v01 = *reinterpret_cast<const bf16x8*>(Vb + voff[ks][1]);
            const bf16x8 v10 = *reinterpret_cast<const bf16x8*>(Vb + 4096 + voff[ks][0]);
            const bf16x8 v11 = *reinterpret_cast<const bf16x8*>(Vb + 4096 + voff[ks][1]);
            __builtin_amdgcn_s_setprio(1);
            o0a = __builtin_amdgcn_mfma_f32_32x32x16_bf16(v00, pa0.v, o0a, 0, 0, 0);
            o0b = __builtin_amdgcn_mfma_f32_32x32x16_bf16(v00, pb0.v, o0b, 0, 0, 0);
            o0a = __builtin_amdgcn_mfma_f32_32x32x16_bf16(v01, pa1.v, o0a, 0, 0, 0);
            o0b = __builtin_amdgcn_mfma_f32_32x32x16_bf16(v01, pb1.v, o0b, 0, 0, 0);
            o1a = __builtin_amdgcn_mfma_f32_32x32x16_bf16(v10, pa0.v, o1a, 0, 0, 0);
            o1b = __builtin_amdgcn_mfma_f32_32x32x16_bf16(v10, pb0.v, o1b, 0, 0, 0);
            o1a = __builtin_amdgcn_mfma_f32_32x32x16_bf16(v11, pa1.v, o1a, 0, 0, 0);
            o1b = __builtin_amdgcn_mfma_f32_32x32x16_bf16(v11, pb1.v, o1b, 0, 0, 0);
            o2a = __builtin_amdgcn_mfma_f32_32x32x16_bf16(onesf.v, pa0.v, o2a, 0, 0, 0);
            o2b = __builtin_amdgcn_mfma_f32_32x32x16_bf16(onesf.v, pb0.v, o2b, 0, 0, 0);
            o2a = __builtin_amdgcn_mfma_f32_32x32x16_bf16(onesf.v, pa1.v, o2a, 0, 0, 0);
            o2b = __builtin_amdgcn_mfma_f32_32x32x16_bf16(onesf.v, pb1.v, o2b, 0, 0, 0);
            __builtin_amdgcn_s_setprio(0);
        }
        cur ^= 1;
    }
    #undef STAGE

    const float rla = 1.0f / o2a[0];
    const float rlb = 1.0f / o2b[0];
    unsigned short* orowa = out + ((size_t)(qbase + q32) * 4 + b) * 1024 + h * 64;
    unsigned short* orowb = orowa + (size_t)32 * 4096;
    #pragma unroll
    for (int q4 = 0; q4 < 4; ++q4) {
        unsigned w0, w1, w2, w3;
        asm("v_cvt_pk_bf16_f32 %0, %1, %2" : "=v"(w0) : "v"(o0a[q4 * 4 + 0] * rla), "v"(o0a[q4 * 4 + 1] * rla));
        asm("v_cvt_pk_bf16_f32 %0, %1, %2" : "=v"(w1) : "v"(o0a[q4 * 4 + 2] * rla), "v"(o0a[q4 * 4 + 3] * rla));
        asm("v_cvt_pk_bf16_f32 %0, %1, %2" : "=v"(w2) : "v"(o1a[q4 * 4 + 0] * rla), "v"(o1a[q4 * 4 + 1] * rla));
        asm("v_cvt_pk_bf16_f32 %0, %1, %2" : "=v"(w3) : "v"(o1a[q4 * 4 + 2] * rla), "v"(o1a[q4 * 4 + 3] * rla));
        uint2 ua; ua.x = w0; ua.y = w1;
        uint2 ub; ub.x = w2; ub.y = w3;
        *reinterpret_cast<uint2*>(orowa + q4 * 8 + hi * 4)      = ua;
        *reinterpret_cast<uint2*>(orowa + 32 + q4 * 8 + hi * 4) = ub;
        asm("v_cvt_pk_bf16_f32 %0, %1, %2" : "=v"(w0) : "v"(o0b[q4 * 4 + 0] * rlb), "v"(o0b[q4 * 4 + 1] * rlb));
        asm("v_cvt_pk_bf16_f32 %0, %1, %2" : "=v"(w1) : "v"(o0b[q4 * 4 + 2] * rlb), "v"(o0b[q4 * 4 + 3] * rlb));
        asm("v_cvt_pk_bf16_f32 %0, %1, %2" : "=v"(w2) : "v"(o1b[q4 * 4 + 0] * rlb), "v"(o1b[q4 * 4 + 1] * rlb));
        asm("v_cvt_pk_bf16_f32 %0, %1, %2" : "=v"(w3) : "v"(o1b[q4 * 4 + 2] * rlb), "v"(o1b[q4 * 4 + 3] * rlb));
        uint2 uc; uc.x = w0; uc.y = w1;
        uint2 ud; ud.x = w2; ud.y = w3;
        *reinterpret_cast<uint2*>(orowb + q4 * 8 + hi * 4)      = uc;
        *reinterpret_cast<uint2*>(orowb + 32 + q4 * 8 + hi * 4) = ud;
    }
}

// ---------------- residual add + LayerNorm: bf16 x + bf16 y -> bf16 or fp32 ----------------
template<int OUTF>
__global__ __launch_bounds__(256) void k_add_ln(
    const unsigned short* __restrict__ x, const unsigned short* __restrict__ y,
    const float* __restrict__ gamma, const float* __restrict__ beta,
    float* __restrict__ outf, unsigned short* __restrict__ outb)
{
    const int row = blockIdx.x * 4 + (threadIdx.x >> 6);
    const int lane = threadIdx.x & 63;
    const size_t base = (size_t)row * 1024;
    float v[16];
    float s = 0.0f, ss = 0.0f;
    #pragma unroll
    for (int i = 0; i < 4; ++i) {
        const int c = lane * 4 + i * 256;
        ushort4 a = *reinterpret_cast<const ushort4*>(x + base + c);
        ushort4 d = *reinterpret_cast<const ushort4*>(y + base + c);
        v[i * 4 + 0] = bf2f(a.x) + bf2f(d.x); v[i * 4 + 1] = bf2f(a.y) + bf2f(d.y);
        v[i * 4 + 2] = bf2f(a.z) + bf2f(d.z); v[i * 4 + 3] = bf2f(a.w) + bf2f(d.w);
        #pragma unroll
        for (int j = 0; j < 4; ++j) { s += v[i * 4 + j]; ss += v[i * 4 + j] * v[i * 4 + j]; }
    }
    #pragma unroll
    for (int o = 1; o < 64; o <<= 1) { s += __shfl_xor(s, o); ss += __shfl_xor(ss, o); }
    const float mu = s * (1.0f / 1024.0f);
    const float var = ss * (1.0f / 1024.0f) - mu * mu;
    const float rstd = rsqrtf(var + 1e-5f);
    #pragma unroll
    for (int i = 0; i < 4; ++i) {
        const int c = lane * 4 + i * 256;
        float4 gq = *reinterpret_cast<const float4*>(gamma + c);
        float4 bq = *reinterpret_cast<const float4*>(beta + c);
        float o0 = (v[i * 4 + 0] - mu) * rstd * gq.x + bq.x;
        float o1 = (v[i * 4 + 1] - mu) * rstd * gq.y + bq.y;
        float o2 = (v[i * 4 + 2] - mu) * rstd * gq.z + bq.z;
        float o3 = (v[i * 4 + 3] - mu) * rstd * gq.w + bq.w;
        if (OUTF) {
            float4 o; o.x = o0; o.y = o1; o.z = o2; o.w = o3;
            *reinterpret_cast<float4*>(outf + base + c) = o;
        } else {
            ushort4 ob;
            ob.x = f2bf(o0); ob.y = f2bf(o1); ob.z = f2bf(o2); ob.w = f2bf(o3);
            *reinterpret_cast<ushort4*>(outb + base + c) = ob;
        }
    }
}

// ---------------- residual + 2 partials + bias, then LayerNorm (fp32 out) ----------------
__global__ __launch_bounds__(256) void k_add_ln3(
    const unsigned short* __restrict__ x,
    const unsigned short* __restrict__ y0, const unsigned short* __restrict__ y1,
    const float* __restrict__ bias,
    const float* __restrict__ gamma, const float* __restrict__ beta,
    float* __restrict__ outf)
{
    const int row = blockIdx.x * 4 + (threadIdx.x >> 6);
    const int lane = threadIdx.x & 63;
    const size_t base = (size_t)row * 1024;
    float v[16];
    float s = 0.0f, ss = 0.0f;
    #pragma unroll
    for (int i = 0; i < 4; ++i) {
        const int c = lane * 4 + i * 256;
        ushort4 a  = *reinterpret_cast<const ushort4*>(x + base + c);
        ushort4 d0 = *reinterpret_cast<const ushort4*>(y0 + base + c);
        ushort4 d1 = *reinterpret_cast<const ushort4*>(y1 + base + c);
        float4 bb  = *reinterpret_cast<const float4*>(bias + c);
        v[i * 4 + 0] = bf2f(a.x) + bf2f(d0.x) + bf2f(d1.x) + bb.x;
        v[i * 4 + 1] = bf2f(a.y) + bf2f(d0.y) + bf2f(d1.y) + bb.y;
        v[i * 4 + 2] = bf2f(a.z) + bf2f(d0.z) + bf2f(d1.z) + bb.z;
        v[i * 4 + 3] = bf2f(a.w) + bf2f(d0.w) + bf2f(d1.w) + bb.w;
        #pragma unroll
        for (int j = 0; j < 4; ++j) { s += v[i * 4 + j]; ss += v[i * 4 + j] * v[i * 4 + j]; }
    }
    #pragma unroll
    for (int o = 1; o < 64; o <<= 1) { s += __shfl_xor(s, o); ss += __shfl_xor(ss, o); }
    const float mu = s * (1.0f / 1024.0f);
    const float var = ss * (1.0f / 1024.0f) - mu * mu;
    const float rstd = rsqrtf(var + 1e-5f);
    #pragma unroll
    for (int i = 0; i < 4; ++i) {
        const int c = lane * 4 + i * 256;
        float4 gq = *reinterpret_cast<const float4*>(gamma + c);
        float4 bq = *reinterpret_cast<const float4*>(beta + c);
        float4 o;
        o.x = (v[i * 4 + 0] - mu) * rstd * gq.x + bq.x;
        o.y = (v[i * 4 + 1] - mu) * rstd * gq.y + bq.y;
        o.z = (v[i * 4 + 2] - mu) * rstd * gq.z + bq.z;
        o.w = (v[i * 4 + 3] - mu) * rstd * gq.w + bq.w;
        *reinterpret_cast<float4*>(outf + base + c) = o;
    }
}

extern "C" void kernel_launch(void* const* d_in, const int* in_sizes, int n_in,
                              void* d_out, int out_size, void* d_ws, size_t ws_size,
                              hipStream_t stream) {
    const float* src  = (const float*)d_in[0];
    const unsigned char* mask = (const unsigned char*)d_in[1];
    const float* w_qkv = (const float*)d_in[2];
    const float* fc_w = (const float*)d_in[3];
    const float* fc_b = (const float*)d_in[4];
    const float* w1   = (const float*)d_in[5];
    const float* b1   = (const float*)d_in[6];
    const float* w2   = (const float*)d_in[7];
    const float* b2   = (const float*)d_in[8];
    const float* g1   = (const float*)d_in[9];
    const float* be1  = (const float*)d_in[10];
    const float* g2   = (const float*)d_in[11];
    const float* be2  = (const float*)d_in[12];
    float* out = (float*)d_out;

    char* ws = (char*)d_ws;
    size_t o = 0;
    auto take = [&](size_t nbytes) { size_t p = o; o += (nbytes + 255) & ~(size_t)255; return p; };
    unsigned short* wqkv_b = (unsigned short*)(ws + take((size_t)3072 * 1024 * 2));
    unsigned short* fcw_b  = (unsigned short*)(ws + take((size_t)1024 * 1024 * 2));
    unsigned short* w1_b   = (unsigned short*)(ws + take((size_t)4096 * 1024 * 2));
    unsigned short* w2_b   = (unsigned short*)(ws + take((size_t)1024 * 4096 * 2));
    unsigned short* src_b  = (unsigned short*)(ws + take((size_t)8192 * 1024 * 2));
    unsigned short* qkv_b  = (unsigned short*)(ws + take((size_t)8192 * 3072 * 2));
    unsigned short* attn_b = (unsigned short*)(ws + take((size_t)8192 * 1024 * 2));
    unsigned short* h_b    = (unsigned short*)(ws + take((size_t)8192 * 4096 * 2));
    unsigned short* proj_b = qkv_b;
    unsigned short* part_b = qkv_b;      // [2][8192*1024] for FFN2 partials
    unsigned short* x1_b   = src_b;      // LN1 rewrites src_b in place
    unsigned short* vt_b   = h_b;

    // 1) fp32 -> bf16 converts (single launch)
    k_cvt5<<<dim3(20480), 256, 0, stream>>>(w_qkv, fc_w, w1, w2, src,
                                            wqkv_b, fcw_b, w1_b, w2_b, src_b);

    // 2) QKV GEMM, BM=128 (grid 768); Q columns pre-scaled by LOG2E/8
    k_gemm8<128, 4, 1><<<dim3((8192 / 128) * (3072 / 256)), 512, 0, stream>>>(
        src_b, wqkv_b, nullptr, qkv_b, nullptr, 8192, 3072, 1024, 1024, 0.18033688011112042f, 0);

    // 2b) V pre-transpose
    k_vtrans<<<dim3(32, 64), 256, 0, stream>>>(qkv_b, vt_b);

    // 3) flash attention (8-wave blocks, 512 q-rows each, 64 q/wave)
    k_attn<<<dim3(256), 512, 0, stream>>>(qkv_b, vt_b, mask, attn_b);

    // 4) output projection (+fc_b), direct BM=128/MF=4, bf16 out
    k_gemm8<128, 4, 1><<<dim3((8192 / 128) * (1024 / 256)), 512, 0, stream>>>(
        attn_b, fcw_b, nullptr, proj_b, fc_b, 8192, 1024, 1024, 0, 1.0f, 0);

    // 5) residual + LN1 -> x1 (bf16, in-place over src_b)
    k_add_ln<0><<<dim3(8192 / 4), 256, 0, stream>>>(src_b, proj_b, g1, be1, nullptr, x1_b);

    // 6) FFN1: relu(x1 @ w1^T + b1), bf16 out
    k_gemm8<256, 8, 1><<<dim3((8192 / 256) * (4096 / 256)), 512, 0, stream>>>(
        x1_b, w1_b, nullptr, h_b, b1, 8192, 4096, 1024, 0, 1.0f, 1);

    // 7) FFN2: split-K=2 (K=2048/part), bf16 partials (b2 folded into LN2)
    k_gemm8<256, 8, 2><<<dim3((8192 / 256) * (1024 / 256) * 2), 512, 0, stream>>>(
        h_b, w2_b, nullptr, part_b, nullptr, 8192, 1024, 4096, 0, 1.0f, 0);

    // 8) x1 + partials + b2, LN2 -> d_out (fp32)
    k_add_ln3<<<dim3(8192 / 4), 256, 0, stream>>>(
        x1_b, part_b, part_b + (size_t)8192 * 1024, b2, g2, be2, out);
}